// Round 3
// baseline (314.856 us; speedup 1.0000x reference)
//
#include <hip/hip_runtime.h>

#define N_BLOCKS 12
#define D 256
#define BATCH 8192

typedef __attribute__((ext_vector_type(8))) short bf16x8;   // 8 bf16 = 4 VGPRs
typedef __attribute__((ext_vector_type(4))) float f32x4;

// fp32 -> bf16 round-to-nearest-even (bit trick; inputs are finite)
__device__ __forceinline__ unsigned short f2bf(float f) {
  unsigned int u = __float_as_uint(f);
  u += 0x7fffu + ((u >> 16) & 1u);
  return (unsigned short)(u >> 16);
}

// async global->LDS, 16B per lane. LDS dest = wave-uniform base + lane*16.
__device__ __forceinline__ void gld16(const unsigned short* g, unsigned short* l) {
  __builtin_amdgcn_global_load_lds(
      (const __attribute__((address_space(1))) unsigned int*)g,
      (__attribute__((address_space(3))) unsigned int*)l,
      16, 0, 0);
}

// ---------------- Pass 1a: X fp32 -> bf16 (straight copy-convert) ----------
__global__ void cvt_x(const float* __restrict__ X, unsigned short* __restrict__ Xb) {
  const long long t = (long long)blockIdx.x * 256 + threadIdx.x;
  const long long base = t * 8;
  const float4 v0 = *(const float4*)(X + base);
  const float4 v1 = *(const float4*)(X + base + 4);
  uint4 r;
  r.x = (unsigned)f2bf(v0.x) | ((unsigned)f2bf(v0.y) << 16);
  r.y = (unsigned)f2bf(v0.z) | ((unsigned)f2bf(v0.w) << 16);
  r.z = (unsigned)f2bf(v1.x) | ((unsigned)f2bf(v1.y) << 16);
  r.w = (unsigned)f2bf(v1.z) | ((unsigned)f2bf(v1.w) << 16);
  *(uint4*)(Xb + base) = r;
}

// ------------- Pass 1b: W[k][i][o] fp32 -> Wt[k][o][i] bf16 (LDS transpose) -
__global__ void cvt_w(const float* __restrict__ W, unsigned short* __restrict__ Wt) {
  __shared__ unsigned short tile[32][33];   // +1 pad vs bank conflicts
  const int k  = blockIdx.x >> 6;
  const int t  = blockIdx.x & 63;
  const int ti = t >> 3;                    // tile row (i dim), 8 tiles
  const int tj = t & 7;                     // tile col (o dim)
  const float* Wk = W + (long long)k * D * D;
  unsigned short* Wtk = Wt + (long long)k * D * D;
  const int lx = threadIdx.x & 31, ly = threadIdx.x >> 5;   // 32x8
  #pragma unroll
  for (int r = 0; r < 4; ++r) {
    const int i = ti * 32 + ly + r * 8;
    const int o = tj * 32 + lx;
    tile[ly + r * 8][lx] = f2bf(Wk[i * D + o]);
  }
  __syncthreads();
  #pragma unroll
  for (int r = 0; r < 4; ++r) {
    const int o = tj * 32 + ly + r * 8;
    const int i = ti * 32 + lx;
    Wtk[o * D + i] = tile[lx][ly + r * 8];
  }
}

// ------------- Pass 2: block-sparse GEMM, B-panel-resident, barrier-free ---
// R0/R1/R2 post-mortem: three different K-tile schedules all land 84-91us
// with every pipe <40% -> the per-K-tile {waitcnt+barrier}x32 coupling of
// all 8 waves IS the bound. New skeleton removes it:
//  - Whole B panel for (i, 64-col slice) = 1024x64 bf16 = 128KB LDS,
//    staged ONCE (one __syncthreads in the entire kernel).
//  - A streams global->VGPR directly (no LDS, no barriers); waves are 8
//    independent pipelined streams; compiler schedules loads freely.
//  - B-LDS row stride 2048B => real 16-way read conflict; fixed by chunk
//    XOR swizzle (chunk ^= n&7), applied BOTH sides: inverse-swizzled
//    global source during gld16 staging + swizzled ds_read (rule #21).
//    2 lanes/bank remain = free (m136).
//  - Per wave 64x64 out, per K-step: 4 A global b128 + 4 B ds_read_b128
//    + 16 MFMA; K fully unrolled (128 steps of k=32 across 4 j-blocks).
//  - XCD decode: 4 bn-siblings of one (i,bm) pair adjacent on one XCD ->
//    A slice read 4x from L2, not HBM. Grid 768 = 3 even rounds x 256 CU.
// MFMA order identical to R0-R2 -> bit-identical output.
__launch_bounds__(512, 2)
__global__ void bs_gemm(const unsigned short* __restrict__ Xb,
                        const unsigned short* __restrict__ Wt,
                        const float* __restrict__ bias,
                        const int* __restrict__ i_idx,
                        const int* __restrict__ j_idx,
                        int nact,
                        float* __restrict__ Y) {
  __shared__ unsigned short sB[65536];   // [n=64][k=1024] bf16, swizzled; 128KB

  // XCD-aware decode: bid&7 -> XCD; per XCD 24 (i,bm) pairs x 4 bn slices.
  const int bid = blockIdx.x;
  const int xcd = bid & 7;
  const int loc = bid >> 3;          // 0..95
  const int bn  = loc & 3;           // 64-col slice
  const int pm  = loc >> 2;          // 0..23
  const int P   = xcd * 24 + pm;     // 0..191
  const int i   = P >> 4;            // output row
  const int bm  = P & 15;            // 512-row slab

  // collect active blocks feeding output row i (pattern gives exactly 4)
  int ks0 = 0, ks1 = 0, ks2 = 0, ks3 = 0, js0 = 0, js1 = 0, js2 = 0, js3 = 0, nk = 0;
  for (int k = 0; k < nact; ++k) {
    if (i_idx[k] == i) {
      const int j = j_idx[k];
      if      (nk == 0) { ks0 = k; js0 = j; }
      else if (nk == 1) { ks1 = k; js1 = j; }
      else if (nk == 2) { ks2 = k; js2 = j; }
      else              { ks3 = k; js3 = j; }
      ++nk;
    }
  }
#define JS(t) ((t) == 0 ? js0 : (t) == 1 ? js1 : (t) == 2 ? js2 : js3)
#define KS(t) ((t) == 0 ? ks0 : (t) == 1 ? ks1 : (t) == 2 ? ks2 : ks3)

  const int tid  = threadIdx.x;
  const int wave = tid >> 6;
  const int lane = tid & 63;
  const int q    = lane >> 4;            // k-quad, 0..3
  const int l15  = lane & 15;

  // ---- stage B once. LDS position p (16B chunks) of row n holds logical
  // chunk p^(n&7); gld16 dest is linear, so fetch logical chunk cc=p^(n&7)
  // from global. Row n covers global k 0..1023 = 4 j-blocks x 256.
  #pragma unroll
  for (int it = 0; it < 16; ++it) {
    const int L  = it * 8192 + tid * 16;       // dest byte 0..131071
    const int n  = L >> 11;                    // B row 0..63
    const int cc = ((L >> 4) & 127) ^ (n & 7); // logical 16B chunk
    const int t  = cc >> 5;                    // j-block (XOR keeps bits<3)
    const unsigned short* src = Wt + (long long)KS(t) * (D * D)
                              + (long long)(bn * 64 + n) * D + (cc & 31) * 8;
    gld16(src, sB + (L >> 1));
  }
  __syncthreads();   // the only barrier in the kernel

  // per-lane constants
  // B read: byte = (nf*16+l15)*2048 + (((kt*4+q) ^ (l15&7))<<4)
  //       = nf*32768 + [bcon ^ ((kt&1)<<6)] + (kt>>1)*128
  const int bcon = l15 * 2048 + ((q ^ (l15 & 3)) << 4) + (((l15 >> 2) & 1) << 6);
  // A: row = bm*512 + wave*64 + mf*16 + l15 ; k-elem = kt*32 + q*8
  const long long arow = ((long long)bm * 512 + wave * 64 + l15) * D + q * 8;

  f32x4 acc[4][4] = {};

  #pragma unroll
  for (int kt = 0; kt < 32; ++kt) {
    const int t  = kt >> 3;               // j-block (compile-time)
    const int kk = kt & 7;                // k-quarter within block
    const unsigned short* Ab =
        Xb + (long long)JS(t) * (BATCH * (long long)D) + arow + kk * 32;
    bf16x8 aF[4], bF[4];
    #pragma unroll
    for (int mf = 0; mf < 4; ++mf)
      aF[mf] = *(const bf16x8*)(Ab + mf * (16 * D));
    const int bb = (bcon ^ ((kt & 1) << 6)) + ((kt >> 1) << 7);
    #pragma unroll
    for (int nf = 0; nf < 4; ++nf)
      bF[nf] = *(const bf16x8*)((const char*)sB + bb + nf * 32768);

    __builtin_amdgcn_s_setprio(1);
    #pragma unroll
    for (int mf = 0; mf < 4; ++mf)
      #pragma unroll
      for (int nf = 0; nf < 4; ++nf)
        acc[mf][nf] = __builtin_amdgcn_mfma_f32_16x16x32_bf16(
            aF[mf], bF[nf], acc[mf][nf], 0, 0, 0);
    __builtin_amdgcn_s_setprio(0);
  }

  // epilogue: C/D layout col=lane&15, row=quad*4+reg; bias folded here
  float* Yb = Y + (long long)i * BATCH * D;
  const int m0 = bm * 512 + wave * 64 + q * 4;
  const int n0 = bn * 64 + l15;
  float bsum[4];
  #pragma unroll
  for (int nf = 0; nf < 4; ++nf) {
    float s = 0.f;
    for (int t = 0; t < nk; ++t) s += bias[KS(t) * D + n0 + nf * 16];
    bsum[nf] = s;
  }
  #pragma unroll
  for (int nf = 0; nf < 4; ++nf) {
    #pragma unroll
    for (int mf = 0; mf < 4; ++mf)
      #pragma unroll
      for (int r2 = 0; r2 < 4; ++r2)
        Yb[(long long)(m0 + mf * 16 + r2) * D + (n0 + nf * 16)] =
            acc[mf][nf][r2] + bsum[nf];
  }
#undef JS
#undef KS
}

extern "C" void kernel_launch(void* const* d_in, const int* in_sizes, int n_in,
                              void* d_out, int out_size, void* d_ws, size_t ws_size,
                              hipStream_t stream) {
  const float* X = (const float*)d_in[0];
  const float* W = (const float*)d_in[1];
  const float* b = (const float*)d_in[2];
  const int* i_idx = (const int*)d_in[3];
  const int* j_idx = (const int*)d_in[4];
  float* Y = (float*)d_out;
  const int nact = in_sizes[3];   // 48

  // workspace layout: Xb (48 MB bf16) | Wt (6 MB bf16, transposed)
  unsigned short* Xb = (unsigned short*)d_ws;
  unsigned short* Wt = (unsigned short*)((char*)d_ws + (size_t)N_BLOCKS * BATCH * D * 2);

  cvt_x<<<(N_BLOCKS * BATCH * D) / (256 * 8), 256, 0, stream>>>(X, Xb);
  cvt_w<<<nact * 64, 256, 0, stream>>>(W, Wt);
  // grid: 8 XCD x 24 (i,bm) pairs x 4 bn = 768 = 3 even rounds of 256 CUs
  bs_gemm<<<768, 512, 0, stream>>>(Xb, Wt, b, i_idx, j_idx, nact, Y);
}

// Round 4
// 251.985 us; speedup vs baseline: 1.2495x; 1.2495x over previous
//
#include <hip/hip_runtime.h>

#define N_BLOCKS 12
#define D 256
#define BATCH 8192

typedef __attribute__((ext_vector_type(8))) short bf16x8;    // 8 bf16 = 4 VGPRs
typedef __attribute__((ext_vector_type(16))) float f32x16;   // 32x32 MFMA acc

// fp32 -> bf16 round-to-nearest-even (bit trick; inputs are finite)
__device__ __forceinline__ unsigned short f2bf(float f) {
  unsigned int u = __float_as_uint(f);
  u += 0x7fffu + ((u >> 16) & 1u);
  return (unsigned short)(u >> 16);
}

// async global->LDS, 16B per lane. LDS dest = wave-uniform base + lane*16.
__device__ __forceinline__ void gld16(const unsigned short* g, unsigned short* l) {
  __builtin_amdgcn_global_load_lds(
      (const __attribute__((address_space(1))) unsigned int*)g,
      (__attribute__((address_space(3))) unsigned int*)l,
      16, 0, 0);
}

// ---------------- Pass 1a: X fp32 -> bf16 (straight copy-convert) ----------
__global__ void cvt_x(const float* __restrict__ X, unsigned short* __restrict__ Xb) {
  const long long t = (long long)blockIdx.x * 256 + threadIdx.x;
  const long long base = t * 8;
  const float4 v0 = *(const float4*)(X + base);
  const float4 v1 = *(const float4*)(X + base + 4);
  uint4 r;
  r.x = (unsigned)f2bf(v0.x) | ((unsigned)f2bf(v0.y) << 16);
  r.y = (unsigned)f2bf(v0.z) | ((unsigned)f2bf(v0.w) << 16);
  r.z = (unsigned)f2bf(v1.x) | ((unsigned)f2bf(v1.y) << 16);
  r.w = (unsigned)f2bf(v1.z) | ((unsigned)f2bf(v1.w) << 16);
  *(uint4*)(Xb + base) = r;
}

// ------------- Pass 1b: W[k][i][o] fp32 -> Wt[k][o][i] bf16 (LDS transpose) -
__global__ void cvt_w(const float* __restrict__ W, unsigned short* __restrict__ Wt) {
  __shared__ unsigned short tile[32][33];   // +1 pad vs bank conflicts
  const int k  = blockIdx.x >> 6;
  const int t  = blockIdx.x & 63;
  const int ti = t >> 3;                    // tile row (i dim), 8 tiles
  const int tj = t & 7;                     // tile col (o dim)
  const float* Wk = W + (long long)k * D * D;
  unsigned short* Wtk = Wt + (long long)k * D * D;
  const int lx = threadIdx.x & 31, ly = threadIdx.x >> 5;   // 32x8
  #pragma unroll
  for (int r = 0; r < 4; ++r) {
    const int i = ti * 32 + ly + r * 8;
    const int o = tj * 32 + lx;
    tile[ly + r * 8][lx] = f2bf(Wk[i * D + o]);
  }
  __syncthreads();
  #pragma unroll
  for (int r = 0; r < 4; ++r) {
    const int o = tj * 32 + ly + r * 8;
    const int i = ti * 32 + lx;
    Wtk[o * D + i] = tile[lx][ly + r * 8];
  }
}

// ------------- Pass 2: block-sparse GEMM, BM=256, BN=128, BK=32 ------------
// R0-R3 post-mortem: LDS DATA PORT is the bound. Wave-tile Wm x Wn gives
// Wm*Wn/(Wm+Wn) FLOP per LDS byte; 64x64 waves (R0-R2) need 127 B/cyc at
// MFMA peak = the whole ~112-128 B/cyc port, before staging writes. Hence
// all three schedules converged to 84-91us / ~25% MfmaUtil.
// Fix: 128x64 wave-tile (42.7 FLOP/B -> 95 B/cyc demand) via
// mfma_f32_32x32x16_bf16, acc[4][2] (128 acc VGPRs), 4 waves/block.
//  - R2's proven pipeline: 3-slot LDS ring (24KB/slot, 72KB -> 2 blocks/CU),
//    prefetch distance 2, ONE barrier per tile, steady wait vmcnt(6).
//    Race-free: STAGE(kt+2) targets slot (kt-1)%3, already read by all
//    waves before barrier kt (lgkmcnt(0) precedes each wave's arrival).
//  - R0's XCD decode: per-XCD 4-wide bm slice; per-(i,XCD) set = A 2MB +
//    B 0.5MB -> L2-resident (R0 measured FETCH 74MB).
//  - Linear LDS, no swizzle (4.0 conflicts/b128 is intrinsic, measured
//    identical across linear/swizzled in R0/R2/R3).
//  - Grid 768 = 8 XCD x 12 i x 4 bm x 2 bn = 3 even rounds of 256 CUs.
__launch_bounds__(256, 2)
__global__ void bs_gemm(const unsigned short* __restrict__ Xb,
                        const unsigned short* __restrict__ Wt,
                        const float* __restrict__ bias,
                        const int* __restrict__ i_idx,
                        const int* __restrict__ j_idx,
                        int nact,
                        float* __restrict__ Y) {
  __shared__ unsigned short lds[3 * 12288];   // 3 slots x 24KB = 72KB

  // XCD-aware decode (dispatch round-robin heuristic)
  const int bid = blockIdx.x;
  const int x   = bid & 7;             // XCD
  const int loc = bid >> 3;            // 0..95
  const int bm  = x * 4 + (loc & 3);   // this XCD's 4-wide bm slice (256-row)
  const int pp  = loc >> 2;            // 0..23, i-major -> temporal locality
  const int i   = pp >> 1;             // output row
  const int bn  = pp & 1;              // 128-col half

  // collect active blocks feeding output row i (pattern gives exactly 4)
  int ks0 = 0, ks1 = 0, ks2 = 0, ks3 = 0, js0 = 0, js1 = 0, js2 = 0, js3 = 0, nk = 0;
  for (int k = 0; k < nact; ++k) {
    if (i_idx[k] == i) {
      const int j = j_idx[k];
      if      (nk == 0) { ks0 = k; js0 = j; }
      else if (nk == 1) { ks1 = k; js1 = j; }
      else if (nk == 2) { ks2 = k; js2 = j; }
      else              { ks3 = k; js3 = j; }
      ++nk;
    }
  }
#define JS(t) ((t) == 0 ? js0 : (t) == 1 ? js1 : (t) == 2 ? js2 : js3)
#define KS(t) ((t) == 0 ? ks0 : (t) == 1 ? ks1 : (t) == 2 ? ks2 : ks3)

  const int tid  = threadIdx.x;
  const int wave = tid >> 6;
  const int lane = tid & 63;
  const int wm   = wave >> 1;            // 0..1 (m half, 128 rows)
  const int wn   = wave & 1;             // 0..1 (n half, 64 cols)
  const int l31  = lane & 31;
  const int lh   = lane >> 5;            // k-half within frag

  // staging: 256 thr x 16B = 4KB = 64 rows x 32k per gld16.
  // A tile 256x32 (16KB) = 4 instrs, B tile 128x32 (8KB) = 2 instrs.
  const int g_off = (tid >> 2) * D + (tid & 3) * 8;

  // frag ds_read byte offsets within slot (linear: row*64B + k*2B)
  // A operand (32x32x16): lane holds row=l31, k = lh*8..lh*8+7 (+kh*16)
  const int aBase = (wm * 128 + l31) * 64 + lh * 16;            // + mf*2048 + kh*32
  const int bBase = 16384 + (wn * 64 + l31) * 64 + lh * 16;     // + nf*2048 + kh*32

  // stage K-tile st (0..31) into slot st%3. 6 loads/thread = 6 vmcnt units.
  auto STAGE = [&](int st) {
    const int t  = st >> 3;              // active-block index (compile-time)
    const int kk = st & 7;               // k-quarter within block (BK=32)
    unsigned short* sl = lds + (st % 3) * 12288;
    const unsigned short* As =
        Xb + ((long long)JS(t) * BATCH + bm * 256) * D + kk * 32 + g_off;
    const unsigned short* Bs =
        Wt + ((long long)KS(t) * D + bn * 128) * D + kk * 32 + g_off;
    gld16(As,           sl + tid * 8);
    gld16(As +  64 * D, sl + 2048  + tid * 8);
    gld16(As + 128 * D, sl + 4096  + tid * 8);
    gld16(As + 192 * D, sl + 6144  + tid * 8);
    gld16(Bs,           sl + 8192  + tid * 8);
    gld16(Bs +  64 * D, sl + 10240 + tid * 8);
  };

  f32x16 acc[4][2] = {};

  STAGE(0); STAGE(1);                    // 12 loads in flight

  #pragma unroll
  for (int kt = 0; kt < 32; ++kt) {
    // retire tile kt's 6 loads; leave tile kt+1's 6 flying (never 0 in-loop)
    if (kt < 31) asm volatile("s_waitcnt vmcnt(6)" ::: "memory");
    else         asm volatile("s_waitcnt vmcnt(0)" ::: "memory");
    __builtin_amdgcn_s_barrier();        // tile-kt stages visible; slot kt-1 free
    __builtin_amdgcn_sched_barrier(0);

    const char* sb = (const char*)lds + (kt % 3) * 24576;
    bf16x8 aF[2][4], bF[2][2];
    #pragma unroll
    for (int kh = 0; kh < 2; ++kh) {
      #pragma unroll
      for (int mf = 0; mf < 4; ++mf)
        aF[kh][mf] = *(const bf16x8*)(sb + aBase + mf * 2048 + kh * 32);
      #pragma unroll
      for (int nf = 0; nf < 2; ++nf)
        bF[kh][nf] = *(const bf16x8*)(sb + bBase + nf * 2048 + kh * 32);
    }

    if (kt < 30) STAGE(kt + 2);          // prefetch distance 2

    asm volatile("s_waitcnt lgkmcnt(0)" ::: "memory");
    __builtin_amdgcn_sched_barrier(0);   // rule #18: pin MFMA below the wait

    __builtin_amdgcn_s_setprio(1);
    #pragma unroll
    for (int kh = 0; kh < 2; ++kh)
      #pragma unroll
      for (int mf = 0; mf < 4; ++mf)
        #pragma unroll
        for (int nf = 0; nf < 2; ++nf)
          acc[mf][nf] = __builtin_amdgcn_mfma_f32_32x32x16_bf16(
              aF[kh][mf], bF[kh][nf], acc[mf][nf], 0, 0, 0);
    __builtin_amdgcn_s_setprio(0);
  }

  // epilogue: 32x32 C/D layout col=lane&31, row=(reg&3)+8*(reg>>2)+4*(lane>>5)
  float* Yb = Y + (long long)i * BATCH * D;
  const int m0 = bm * 256 + wm * 128;
  const int n0 = bn * 128 + wn * 64 + l31;
  float bsum[2];
  #pragma unroll
  for (int nf = 0; nf < 2; ++nf) {
    float s = 0.f;
    for (int t = 0; t < nk; ++t) s += bias[KS(t) * D + n0 + nf * 32];
    bsum[nf] = s;
  }
  #pragma unroll
  for (int nf = 0; nf < 2; ++nf)
    #pragma unroll
    for (int mf = 0; mf < 4; ++mf)
      #pragma unroll
      for (int rg = 0; rg < 16; ++rg) {
        const int row = (rg & 3) + 8 * (rg >> 2) + 4 * lh;
        Yb[(long long)(m0 + mf * 32 + row) * D + (n0 + nf * 32)] =
            acc[mf][nf][rg] + bsum[nf];
      }
#undef JS
#undef KS
}

extern "C" void kernel_launch(void* const* d_in, const int* in_sizes, int n_in,
                              void* d_out, int out_size, void* d_ws, size_t ws_size,
                              hipStream_t stream) {
  const float* X = (const float*)d_in[0];
  const float* W = (const float*)d_in[1];
  const float* b = (const float*)d_in[2];
  const int* i_idx = (const int*)d_in[3];
  const int* j_idx = (const int*)d_in[4];
  float* Y = (float*)d_out;
  const int nact = in_sizes[3];   // 48

  // workspace layout: Xb (48 MB bf16) | Wt (6 MB bf16, transposed)
  unsigned short* Xb = (unsigned short*)d_ws;
  unsigned short* Wt = (unsigned short*)((char*)d_ws + (size_t)N_BLOCKS * BATCH * D * 2);

  cvt_x<<<(N_BLOCKS * BATCH * D) / (256 * 8), 256, 0, stream>>>(X, Xb);
  cvt_w<<<nact * 64, 256, 0, stream>>>(W, Wt);
  // grid: 8 XCD x (12 i x 2 bn x 4 bm) = 768 = 3 even rounds of 256 CUs
  bs_gemm<<<768, 256, 0, stream>>>(Xb, Wt, b, i_idx, j_idx, nact, Y);
}

// Round 5
// 249.435 us; speedup vs baseline: 1.2623x; 1.0102x over previous
//
#include <hip/hip_runtime.h>

#define N_BLOCKS 12
#define D 256
#define BATCH 8192

typedef __attribute__((ext_vector_type(8))) short bf16x8;    // 8 bf16 = 4 VGPRs
typedef __attribute__((ext_vector_type(16))) float f32x16;   // 32x32 MFMA acc

// fp32 -> bf16 round-to-nearest-even (bit trick; inputs are finite)
__device__ __forceinline__ unsigned short f2bf(float f) {
  unsigned int u = __float_as_uint(f);
  u += 0x7fffu + ((u >> 16) & 1u);
  return (unsigned short)(u >> 16);
}

// async global->LDS, 16B per lane. LDS dest = wave-uniform base + lane*16.
__device__ __forceinline__ void gld16(const unsigned short* g, unsigned short* l) {
  __builtin_amdgcn_global_load_lds(
      (const __attribute__((address_space(1))) unsigned int*)g,
      (__attribute__((address_space(3))) unsigned int*)l,
      16, 0, 0);
}

// ---------------- Pass 1a: X fp32 -> bf16 (straight copy-convert) ----------
__global__ void cvt_x(const float* __restrict__ X, unsigned short* __restrict__ Xb) {
  const long long t = (long long)blockIdx.x * 256 + threadIdx.x;
  const long long base = t * 8;
  const float4 v0 = *(const float4*)(X + base);
  const float4 v1 = *(const float4*)(X + base + 4);
  uint4 r;
  r.x = (unsigned)f2bf(v0.x) | ((unsigned)f2bf(v0.y) << 16);
  r.y = (unsigned)f2bf(v0.z) | ((unsigned)f2bf(v0.w) << 16);
  r.z = (unsigned)f2bf(v1.x) | ((unsigned)f2bf(v1.y) << 16);
  r.w = (unsigned)f2bf(v1.z) | ((unsigned)f2bf(v1.w) << 16);
  *(uint4*)(Xb + base) = r;
}

// ------------- Pass 1b: W[k][i][o] fp32 -> Wt[k][o][i] bf16 (LDS transpose) -
__global__ void cvt_w(const float* __restrict__ W, unsigned short* __restrict__ Wt) {
  __shared__ unsigned short tile[32][33];   // +1 pad vs bank conflicts
  const int k  = blockIdx.x >> 6;
  const int t  = blockIdx.x & 63;
  const int ti = t >> 3;                    // tile row (i dim), 8 tiles
  const int tj = t & 7;                     // tile col (o dim)
  const float* Wk = W + (long long)k * D * D;
  unsigned short* Wtk = Wt + (long long)k * D * D;
  const int lx = threadIdx.x & 31, ly = threadIdx.x >> 5;   // 32x8
  #pragma unroll
  for (int r = 0; r < 4; ++r) {
    const int i = ti * 32 + ly + r * 8;
    const int o = tj * 32 + lx;
    tile[ly + r * 8][lx] = f2bf(Wk[i * D + o]);
  }
  __syncthreads();
  #pragma unroll
  for (int r = 0; r < 4; ++r) {
    const int o = tj * 32 + ly + r * 8;
    const int i = ti * 32 + lx;
    Wtk[o * D + i] = tile[lx][ly + r * 8];
  }
}

// ------------- Pass 2: block-sparse GEMM, BM=256, BN=128, BK=32 ------------
// R4 post-mortem: fat 128x64 waves fixed the port-demand ratio but the
// 32x32 fragment read pattern raised bank conflicts to 12.0/ds_read_b128
// (vs the 4.0/read floor of R0-R3): each read touches 32 rows x (1 of 4)
// 16B chunks, row stride 64B = 16-bank stride -> 16 lanes per 4-bank group.
// 14.16M extra cycles = 23us of stall on a ~23us-minimum port.
// FIX: k-chunk XOR swizzle keyed on row bits [2:1]. Logical chunk c of row
// r lives at position c ^ ((r>>1)&3). Lanes cycle (r>>1)&3 over 0..3 ->
// every bank gets exactly 8 words/read = intrinsic minimum, for A and B.
// Both-sides-or-neither (rule 21): linear gld16 dest + inverse-swizzled
// GLOBAL source chunk ((tid&3)^((tid>>3)&3); staged sub-blocks are 64 rows
// so one formula serves all 6 loads) + same XOR on ds_read.
// Rest unchanged from R4 (3-slot ring, vmcnt(6), one barrier/tile, XCD
// decode, setprio). Bit-identical MFMA order -> same absmax.
__launch_bounds__(256, 2)
__global__ void bs_gemm(const unsigned short* __restrict__ Xb,
                        const unsigned short* __restrict__ Wt,
                        const float* __restrict__ bias,
                        const int* __restrict__ i_idx,
                        const int* __restrict__ j_idx,
                        int nact,
                        float* __restrict__ Y) {
  __shared__ unsigned short lds[3 * 12288];   // 3 slots x 24KB = 72KB

  // XCD-aware decode (dispatch round-robin heuristic)
  const int bid = blockIdx.x;
  const int x   = bid & 7;             // XCD
  const int loc = bid >> 3;            // 0..95
  const int bm  = x * 4 + (loc & 3);   // this XCD's 4-wide bm slice (256-row)
  const int pp  = loc >> 2;            // 0..23, i-major -> temporal locality
  const int i   = pp >> 1;             // output row
  const int bn  = pp & 1;              // 128-col half

  // collect active blocks feeding output row i (pattern gives exactly 4)
  int ks0 = 0, ks1 = 0, ks2 = 0, ks3 = 0, js0 = 0, js1 = 0, js2 = 0, js3 = 0, nk = 0;
  for (int k = 0; k < nact; ++k) {
    if (i_idx[k] == i) {
      const int j = j_idx[k];
      if      (nk == 0) { ks0 = k; js0 = j; }
      else if (nk == 1) { ks1 = k; js1 = j; }
      else if (nk == 2) { ks2 = k; js2 = j; }
      else              { ks3 = k; js3 = j; }
      ++nk;
    }
  }
#define JS(t) ((t) == 0 ? js0 : (t) == 1 ? js1 : (t) == 2 ? js2 : js3)
#define KS(t) ((t) == 0 ? ks0 : (t) == 1 ? ks1 : (t) == 2 ? ks2 : ks3)

  const int tid  = threadIdx.x;
  const int wave = tid >> 6;
  const int lane = tid & 63;
  const int wm   = wave >> 1;            // 0..1 (m half, 128 rows)
  const int wn   = wave & 1;             // 0..1 (n half, 64 cols)
  const int l31  = lane & 31;
  const int lh   = lane >> 5;            // k-half within frag

  // staging source: row = tid>>2, logical chunk = (tid&3) ^ ((r>>1)&3).
  // Staged sub-blocks are 64 rows (64*... >>1 is mult of 4), so (r>>1)&3 =
  // (tid>>3)&3 for every gld16 below.
  const int g_off = (tid >> 2) * D + (((tid & 3) ^ ((tid >> 3) & 3)) * 8);

  // frag ds_read offsets: row base linear, chunk position XOR-swizzled.
  // A/B rows differ from l31 by multiples of 8 -> (row>>1)&3 == (l31>>1)&3.
  const int sw = (l31 >> 1) & 3;
  const int cko0 = ((0 + lh) ^ sw) << 4;     // kh=0 chunk byte offset
  const int cko1 = ((2 + lh) ^ sw) << 4;     // kh=1 chunk byte offset
  const int aBase = (wm * 128 + l31) * 64;            // + mf*2048 + cko
  const int bBase = 16384 + (wn * 64 + l31) * 64;     // + nf*2048 + cko

  // stage K-tile st (0..31) into slot st%3. 6 loads/thread = 6 vmcnt units.
  auto STAGE = [&](int st) {
    const int t  = st >> 3;              // active-block index (compile-time)
    const int kk = st & 7;               // k-quarter within block (BK=32)
    unsigned short* sl = lds + (st % 3) * 12288;
    const unsigned short* As =
        Xb + ((long long)JS(t) * BATCH + bm * 256) * D + kk * 32 + g_off;
    const unsigned short* Bs =
        Wt + ((long long)KS(t) * D + bn * 128) * D + kk * 32 + g_off;
    gld16(As,           sl + tid * 8);
    gld16(As +  64 * D, sl + 2048  + tid * 8);
    gld16(As + 128 * D, sl + 4096  + tid * 8);
    gld16(As + 192 * D, sl + 6144  + tid * 8);
    gld16(Bs,           sl + 8192  + tid * 8);
    gld16(Bs +  64 * D, sl + 10240 + tid * 8);
  };

  f32x16 acc[4][2] = {};

  STAGE(0); STAGE(1);                    // 12 loads in flight

  #pragma unroll
  for (int kt = 0; kt < 32; ++kt) {
    // retire tile kt's 6 loads; leave tile kt+1's 6 flying (never 0 in-loop)
    if (kt < 31) asm volatile("s_waitcnt vmcnt(6)" ::: "memory");
    else         asm volatile("s_waitcnt vmcnt(0)" ::: "memory");
    __builtin_amdgcn_s_barrier();        // tile-kt stages visible; slot kt-1 free
    __builtin_amdgcn_sched_barrier(0);

    const char* sb = (const char*)lds + (kt % 3) * 24576;
    bf16x8 aF[2][4], bF[2][2];
    #pragma unroll
    for (int mf = 0; mf < 4; ++mf) {
      aF[0][mf] = *(const bf16x8*)(sb + aBase + mf * 2048 + cko0);
      aF[1][mf] = *(const bf16x8*)(sb + aBase + mf * 2048 + cko1);
    }
    #pragma unroll
    for (int nf = 0; nf < 2; ++nf) {
      bF[0][nf] = *(const bf16x8*)(sb + bBase + nf * 2048 + cko0);
      bF[1][nf] = *(const bf16x8*)(sb + bBase + nf * 2048 + cko1);
    }

    if (kt < 30) STAGE(kt + 2);          // prefetch distance 2

    asm volatile("s_waitcnt lgkmcnt(0)" ::: "memory");
    __builtin_amdgcn_sched_barrier(0);   // rule #18: pin MFMA below the wait

    __builtin_amdgcn_s_setprio(1);
    #pragma unroll
    for (int kh = 0; kh < 2; ++kh)
      #pragma unroll
      for (int mf = 0; mf < 4; ++mf)
        #pragma unroll
        for (int nf = 0; nf < 2; ++nf)
          acc[mf][nf] = __builtin_amdgcn_mfma_f32_32x32x16_bf16(
              aF[kh][mf], bF[kh][nf], acc[mf][nf], 0, 0, 0);
    __builtin_amdgcn_s_setprio(0);
  }

  // epilogue: 32x32 C/D layout col=lane&31, row=(reg&3)+8*(reg>>2)+4*(lane>>5)
  float* Yb = Y + (long long)i * BATCH * D;
  const int m0 = bm * 256 + wm * 128;
  const int n0 = bn * 128 + wn * 64 + l31;
  float bsum[2];
  #pragma unroll
  for (int nf = 0; nf < 2; ++nf) {
    float s = 0.f;
    for (int t = 0; t < nk; ++t) s += bias[KS(t) * D + n0 + nf * 32];
    bsum[nf] = s;
  }
  #pragma unroll
  for (int nf = 0; nf < 2; ++nf)
    #pragma unroll
    for (int mf = 0; mf < 4; ++mf)
      #pragma unroll
      for (int rg = 0; rg < 16; ++rg) {
        const int row = (rg & 3) + 8 * (rg >> 2) + 4 * lh;
        Yb[(long long)(m0 + mf * 32 + row) * D + (n0 + nf * 32)] =
            acc[mf][nf][rg] + bsum[nf];
      }
#undef JS
#undef KS
}

extern "C" void kernel_launch(void* const* d_in, const int* in_sizes, int n_in,
                              void* d_out, int out_size, void* d_ws, size_t ws_size,
                              hipStream_t stream) {
  const float* X = (const float*)d_in[0];
  const float* W = (const float*)d_in[1];
  const float* b = (const float*)d_in[2];
  const int* i_idx = (const int*)d_in[3];
  const int* j_idx = (const int*)d_in[4];
  float* Y = (float*)d_out;
  const int nact = in_sizes[3];   // 48

  // workspace layout: Xb (48 MB bf16) | Wt (6 MB bf16, transposed)
  unsigned short* Xb = (unsigned short*)d_ws;
  unsigned short* Wt = (unsigned short*)((char*)d_ws + (size_t)N_BLOCKS * BATCH * D * 2);

  cvt_x<<<(N_BLOCKS * BATCH * D) / (256 * 8), 256, 0, stream>>>(X, Xb);
  cvt_w<<<nact * 64, 256, 0, stream>>>(W, Wt);
  // grid: 8 XCD x (12 i x 2 bn x 4 bm) = 768 = 3 even rounds of 256 CUs
  bs_gemm<<<768, 256, 0, stream>>>(Xb, Wt, b, i_idx, j_idx, nact, Y);
}